// Round 1
// baseline (805.535 us; speedup 1.0000x reference)
//
#include <hip/hip_runtime.h>
#include <hip/hip_bf16.h>
#include <stdint.h>

typedef __attribute__((ext_vector_type(8))) __bf16 bf16x8;
typedef __attribute__((ext_vector_type(4))) float f32x4;

#define IN_F   4096
#define OUT_F  4096
#define M_ROWS 16384   // 8 * 2048

static __device__ __forceinline__ unsigned short f2bf(float f) {
    unsigned int u = __float_as_uint(f);
    u += 0x7FFFu + ((u >> 16) & 1u);   // round-to-nearest-even
    return (unsigned short)(u >> 16);
}

// ---------------------------------------------------------------------------
// Kernel 1: build full weight (OUT_F x IN_F) in bf16.
// W[n][k] = weight[n][k] + s0[k0][n0]*s1[k1][n1]*s2[k2][n2]*s3[k3][n3]
// where k = k0*512 + k1*64 + k2*8 + k3 (base-8 digits), n likewise.
// s[o][a][b] = sum_r leafs[o][r][a][b]   (a = in-digit, b = out-digit)
// ---------------------------------------------------------------------------
__global__ __launch_bounds__(256) void build_w_kernel(
    const float* __restrict__ weight, const float* __restrict__ leafs,
    unsigned short* __restrict__ wb)
{
    __shared__ float s[4][8][8];
    const int t = threadIdx.x;
    {
        const int o = t >> 6, a = (t >> 3) & 7, b = t & 7;
        float acc = 0.f;
        #pragma unroll
        for (int r = 0; r < 8; ++r)
            acc += leafs[o * 512 + r * 64 + a * 8 + b];
        s[o][a][b] = acc;
    }
    __syncthreads();

    const int total = (OUT_F * IN_F) / 8;   // groups of 8 along k
    for (int idx = blockIdx.x * 256 + t; idx < total; idx += gridDim.x * 256) {
        const int n  = idx >> 9;        // 0..4095 (out index)
        const int kg = idx & 511;       // k-group (k = kg*8 + k3)
        const int n0 = n >> 9, n1 = (n >> 6) & 7, n2 = (n >> 3) & 7, n3 = n & 7;
        const int k0 = kg >> 6, k1 = (kg >> 3) & 7, k2 = kg & 7;
        const float p = s[0][k0][n0] * s[1][k1][n1] * s[2][k2][n2];
        const float4* wp = (const float4*)(weight + (size_t)n * IN_F + kg * 8);
        const float4 w0 = wp[0], w1 = wp[1];
        const float wv[8] = {w0.x, w0.y, w0.z, w0.w, w1.x, w1.y, w1.z, w1.w};
        unsigned int pk[4];
        #pragma unroll
        for (int j = 0; j < 4; ++j) {
            unsigned int lo = f2bf(wv[2*j]   + p * s[3][2*j]  [n3]);
            unsigned int hi = f2bf(wv[2*j+1] + p * s[3][2*j+1][n3]);
            pk[j] = lo | (hi << 16);
        }
        *reinterpret_cast<uint4*>(wb + (size_t)n * IN_F + kg * 8) =
            make_uint4(pk[0], pk[1], pk[2], pk[3]);
    }
}

// ---------------------------------------------------------------------------
// Kernel 2: x fp32 -> bf16, 8 elements/thread, grid-stride.
// ---------------------------------------------------------------------------
__global__ __launch_bounds__(256) void conv_x_kernel(
    const float* __restrict__ x, unsigned short* __restrict__ xb, long long n8)
{
    for (long long idx = (long long)blockIdx.x * 256 + threadIdx.x; idx < n8;
         idx += (long long)gridDim.x * 256) {
        const float4* xp = (const float4*)(x + idx * 8);
        const float4 a = xp[0], b = xp[1];
        const float v[8] = {a.x, a.y, a.z, a.w, b.x, b.y, b.z, b.w};
        unsigned int pk[4];
        #pragma unroll
        for (int j = 0; j < 4; ++j)
            pk[j] = (unsigned int)f2bf(v[2*j]) | ((unsigned int)f2bf(v[2*j+1]) << 16);
        *reinterpret_cast<uint4*>(xb + idx * 8) = make_uint4(pk[0], pk[1], pk[2], pk[3]);
    }
}

// ---------------------------------------------------------------------------
// Kernel 3: GEMM  out[m][n] = sum_k x[m][k] * W[n][k] + bias[n]
// m97-ladder structure: 128x128 tile, BK=32, 256 threads (4 waves, 2x2),
// each wave a 64x64 subtile = 4x4 fragments of mfma_f32_16x16x32_bf16.
// A and B staged via global_load_lds width=16 (linear [128][32] LDS tiles).
// ---------------------------------------------------------------------------
#define BM 128
#define BN 128
#define BK 32

template <bool XBF16>
__global__ __launch_bounds__(256) void gemm_kernel(
    const unsigned short* __restrict__ xb,   // bf16 x (used if XBF16)
    const float* __restrict__ xf,            // fp32 x (used if !XBF16)
    const unsigned short* __restrict__ wb,   // bf16 full weight (OUT_F x IN_F)
    const float* __restrict__ bias,
    float* __restrict__ out)
{
    __shared__ unsigned short As[BM * BK];   // 8 KB
    __shared__ unsigned short Bs[BN * BK];   // 8 KB

    const int t    = threadIdx.x;
    const int wave = t >> 6;
    const int lane = t & 63;
    const int lr   = lane & 15;    // fragment row/col within 16
    const int kq   = lane >> 4;    // k-quarter 0..3
    const int wr   = wave >> 1;    // wave row 0..1
    const int wc   = wave & 1;     // wave col 0..1

    const int bm = blockIdx.x * BM;
    const int bn = blockIdx.y * BN;

    // staging map: thread t owns 16B at LDS byte offset t*16 (linear),
    // i.e. row = t/4 (within a 64-row half), col = (t&3)*8 elements.
    const int srow = t >> 2;
    const int scol = (t & 3) * 8;

    f32x4 acc[4][4] = {};

    for (int kt = 0; kt < IN_F; kt += BK) {
        // ---- stage A (x tile, 128x32) ----
        if (XBF16) {
            const unsigned short* ga0 = xb + (size_t)(bm + srow) * IN_F + kt + scol;
            const unsigned short* ga1 = ga0 + (size_t)64 * IN_F;
            __builtin_amdgcn_global_load_lds(
                (const __attribute__((address_space(1))) void*)ga0,
                (__attribute__((address_space(3))) void*)(As + srow * BK + scol), 16, 0, 0);
            __builtin_amdgcn_global_load_lds(
                (const __attribute__((address_space(1))) void*)ga1,
                (__attribute__((address_space(3))) void*)(As + (64 + srow) * BK + scol), 16, 0, 0);
        } else {
            #pragma unroll
            for (int g = 0; g < 2; ++g) {
                const int row = srow + g * 64;
                const float4* xp =
                    (const float4*)(xf + (size_t)(bm + row) * IN_F + kt + scol);
                const float4 a0 = xp[0], a1 = xp[1];
                const float v[8] = {a0.x, a0.y, a0.z, a0.w, a1.x, a1.y, a1.z, a1.w};
                unsigned int pk[4];
                #pragma unroll
                for (int j = 0; j < 4; ++j)
                    pk[j] = (unsigned int)f2bf(v[2*j]) |
                            ((unsigned int)f2bf(v[2*j+1]) << 16);
                *reinterpret_cast<uint4*>(&As[row * BK + scol]) =
                    make_uint4(pk[0], pk[1], pk[2], pk[3]);
            }
        }
        // ---- stage B (W tile, 128x32) ----
        {
            const unsigned short* gb0 = wb + (size_t)(bn + srow) * IN_F + kt + scol;
            const unsigned short* gb1 = gb0 + (size_t)64 * IN_F;
            __builtin_amdgcn_global_load_lds(
                (const __attribute__((address_space(1))) void*)gb0,
                (__attribute__((address_space(3))) void*)(Bs + srow * BK + scol), 16, 0, 0);
            __builtin_amdgcn_global_load_lds(
                (const __attribute__((address_space(1))) void*)gb1,
                (__attribute__((address_space(3))) void*)(Bs + (64 + srow) * BK + scol), 16, 0, 0);
        }
        __syncthreads();

        bf16x8 af[4], bfr[4];
        #pragma unroll
        for (int m = 0; m < 4; ++m)
            af[m] = *reinterpret_cast<const bf16x8*>(
                As + (wr * 64 + m * 16 + lr) * BK + kq * 8);
        #pragma unroll
        for (int n = 0; n < 4; ++n)
            bfr[n] = *reinterpret_cast<const bf16x8*>(
                Bs + (wc * 64 + n * 16 + lr) * BK + kq * 8);

        #pragma unroll
        for (int m = 0; m < 4; ++m)
            #pragma unroll
            for (int n = 0; n < 4; ++n)
                acc[m][n] = __builtin_amdgcn_mfma_f32_16x16x32_bf16(
                    af[m], bfr[n], acc[m][n], 0, 0, 0);

        __syncthreads();
    }

    // ---- epilogue: C/D layout col=lane&15, row=(lane>>4)*4+j ----
    const int crow0 = kq * 4;
    #pragma unroll
    for (int n = 0; n < 4; ++n) {
        const int col = bn + wc * 64 + n * 16 + lr;
        const float bv = bias[col];
        #pragma unroll
        for (int m = 0; m < 4; ++m) {
            const int rowb = bm + wr * 64 + m * 16 + crow0;
            #pragma unroll
            for (int j = 0; j < 4; ++j)
                out[(size_t)(rowb + j) * OUT_F + col] = acc[m][n][j] + bv;
        }
    }
}

// ---------------------------------------------------------------------------
extern "C" void kernel_launch(void* const* d_in, const int* in_sizes, int n_in,
                              void* d_out, int out_size, void* d_ws, size_t ws_size,
                              hipStream_t stream) {
    const float* x      = (const float*)d_in[0];
    const float* weight = (const float*)d_in[1];
    const float* bias   = (const float*)d_in[2];
    const float* leafs  = (const float*)d_in[3];
    float* out = (float*)d_out;

    unsigned short* wb = (unsigned short*)d_ws;                    // 32 MB
    unsigned short* xb = (unsigned short*)((char*)d_ws +
                         (size_t)OUT_F * IN_F * sizeof(unsigned short));

    const size_t need_full = (size_t)OUT_F * IN_F * 2 + (size_t)M_ROWS * IN_F * 2;
    const bool xbf = ws_size >= need_full;

    build_w_kernel<<<dim3(2048), dim3(256), 0, stream>>>(weight, leafs, wb);

    dim3 grid(M_ROWS / BM, OUT_F / BN);
    if (xbf) {
        conv_x_kernel<<<dim3(2048), dim3(256), 0, stream>>>(
            x, xb, (long long)M_ROWS * IN_F / 8);
        gemm_kernel<true><<<grid, dim3(256), 0, stream>>>(xb, x, wb, bias, out);
    } else {
        gemm_kernel<false><<<grid, dim3(256), 0, stream>>>(xb, x, wb, bias, out);
    }
}

// Round 2
// 650.819 us; speedup vs baseline: 1.2377x; 1.2377x over previous
//
#include <hip/hip_runtime.h>
#include <hip/hip_bf16.h>
#include <stdint.h>

typedef __attribute__((ext_vector_type(8))) __bf16 bf16x8;
typedef __attribute__((ext_vector_type(4))) float f32x4;

#define IN_F   4096
#define OUT_F  4096
#define M_ROWS 16384   // 8 * 2048

static __device__ __forceinline__ unsigned short f2bf(float f) {
    unsigned int u = __float_as_uint(f);
    u += 0x7FFFu + ((u >> 16) & 1u);   // round-to-nearest-even
    return (unsigned short)(u >> 16);
}

// ---------------------------------------------------------------------------
// Kernel 1: build full weight (OUT_F x IN_F) in bf16.
// W[n][k] = weight[n][k] + s0[k0][n0]*s1[k1][n1]*s2[k2][n2]*s3[k3][n3]
// ---------------------------------------------------------------------------
__global__ __launch_bounds__(256) void build_w_kernel(
    const float* __restrict__ weight, const float* __restrict__ leafs,
    unsigned short* __restrict__ wb)
{
    __shared__ float s[4][8][8];
    const int t = threadIdx.x;
    {
        const int o = t >> 6, a = (t >> 3) & 7, b = t & 7;
        float acc = 0.f;
        #pragma unroll
        for (int r = 0; r < 8; ++r)
            acc += leafs[o * 512 + r * 64 + a * 8 + b];
        s[o][a][b] = acc;
    }
    __syncthreads();

    const int total = (OUT_F * IN_F) / 8;
    for (int idx = blockIdx.x * 256 + t; idx < total; idx += gridDim.x * 256) {
        const int n  = idx >> 9;
        const int kg = idx & 511;
        const int n0 = n >> 9, n1 = (n >> 6) & 7, n2 = (n >> 3) & 7, n3 = n & 7;
        const int k0 = kg >> 6, k1 = (kg >> 3) & 7, k2 = kg & 7;
        const float p = s[0][k0][n0] * s[1][k1][n1] * s[2][k2][n2];
        const float4* wp = (const float4*)(weight + (size_t)n * IN_F + kg * 8);
        const float4 w0 = wp[0], w1 = wp[1];
        const float wv[8] = {w0.x, w0.y, w0.z, w0.w, w1.x, w1.y, w1.z, w1.w};
        unsigned int pk[4];
        #pragma unroll
        for (int j = 0; j < 4; ++j) {
            unsigned int lo = f2bf(wv[2*j]   + p * s[3][2*j]  [n3]);
            unsigned int hi = f2bf(wv[2*j+1] + p * s[3][2*j+1][n3]);
            pk[j] = lo | (hi << 16);
        }
        *reinterpret_cast<uint4*>(wb + (size_t)n * IN_F + kg * 8) =
            make_uint4(pk[0], pk[1], pk[2], pk[3]);
    }
}

// ---------------------------------------------------------------------------
// Kernel 2: x fp32 -> bf16
// ---------------------------------------------------------------------------
__global__ __launch_bounds__(256) void conv_x_kernel(
    const float* __restrict__ x, unsigned short* __restrict__ xb, long long n8)
{
    for (long long idx = (long long)blockIdx.x * 256 + threadIdx.x; idx < n8;
         idx += (long long)gridDim.x * 256) {
        const float4* xp = (const float4*)(x + idx * 8);
        const float4 a = xp[0], b = xp[1];
        const float v[8] = {a.x, a.y, a.z, a.w, b.x, b.y, b.z, b.w};
        unsigned int pk[4];
        #pragma unroll
        for (int j = 0; j < 4; ++j)
            pk[j] = (unsigned int)f2bf(v[2*j]) | ((unsigned int)f2bf(v[2*j+1]) << 16);
        *reinterpret_cast<uint4*>(xb + idx * 8) = make_uint4(pk[0], pk[1], pk[2], pk[3]);
    }
}

// ---------------------------------------------------------------------------
// Kernel 3: 256x256 8-phase GEMM (T1 XCD swizzle, T2 LDS swizzle, T3/T4
// counted-vmcnt 8-phase schedule, T5 setprio).
// LDS: A panels [2 dbuf][2 kk][256 rows][32 cols] bf16 at byte 0,
//      B panels same at byte 65536. Panel = 16384 B.
// Element (row, col) of a panel lives at byte row*64 + ((col*2) ^ ((row&6)<<3)).
// Staged linearly by global_load_lds from inverse-swizzled global addresses.
// ---------------------------------------------------------------------------
#define BK 64
#define NT (IN_F / BK)   // 64

#define PANEL_A(b,kk) (ldsb + ((b)*2+(kk))*16384)
#define PANEL_B(b,kk) (ldsb + 65536 + ((b)*2+(kk))*16384)

#define GLL(src, dst) __builtin_amdgcn_global_load_lds( \
    (const __attribute__((address_space(1))) void*)(src), \
    (__attribute__((address_space(3))) void*)(dst), 16, 0, 0)

#define STAGE_A(b, kk, ko) do { \
    GLL(sA1 + (ko) + (kk)*32, PANEL_A(b,kk) + d1); \
    GLL(sA2 + (ko) + (kk)*32, PANEL_A(b,kk) + d2); } while(0)
#define STAGE_B(b, kk, ko) do { \
    GLL(sB1 + (ko) + (kk)*32, PANEL_B(b,kk) + d1); \
    GLL(sB2 + (ko) + (kk)*32, PANEL_B(b,kk) + d2); } while(0)

__global__ __launch_bounds__(512, 2) void gemm8_kernel(
    const unsigned short* __restrict__ xb,   // bf16 x [M_ROWS][IN_F]
    const unsigned short* __restrict__ wb,   // bf16 W [OUT_F][IN_F]
    const float* __restrict__ bias,
    float* __restrict__ out)
{
    __shared__ unsigned short lds_us[65536];   // 128 KiB
    char* const ldsb = (char*)lds_us;

    const int t    = threadIdx.x;
    const int wave = t >> 6;
    const int lane = t & 63;
    const int lr   = lane & 15;
    const int kq   = lane >> 4;
    const int wr   = wave >> 2;      // 0..1  (M)
    const int wcn  = wave & 3;       // 0..3  (N)
    const int sx   = (lr & 6) << 3;  // read-side swizzle XOR (bytes)

    // XCD-aware bijective block swizzle (1024 blocks, 1024 % 8 == 0)
    const int nwg  = gridDim.x;
    const int bid  = blockIdx.x;
    const int swzb = (bid & 7) * (nwg >> 3) + (bid >> 3);
    const int bm   = (swzb & 63) * 256;   // 64 M-tiles
    const int bn   = (swzb >> 6) * 256;   // 16 N-tiles

    // staging constants: thread covers 16B chunks c1, c2 of each panel
    const int c1 = t, c2 = t + 512;
    const int r1 = c1 >> 2, r2 = c2 >> 2;                 // panel row
    const int q1 = ((c1 & 3) * 16) ^ ((r1 & 6) << 3);     // inv-swizzled src byte
    const int q2 = ((c2 & 3) * 16) ^ ((r2 & 6) << 3);
    const unsigned short* sA1 = xb + (size_t)(bm + r1) * IN_F + (q1 >> 1);
    const unsigned short* sA2 = xb + (size_t)(bm + r2) * IN_F + (q2 >> 1);
    const unsigned short* sB1 = wb + (size_t)(bn + r1) * IN_F + (q1 >> 1);
    const unsigned short* sB2 = wb + (size_t)(bn + r2) * IN_F + (q2 >> 1);
    const int d1 = c1 * 16, d2 = c2 * 16;                 // lds dest (linear)

    // per-lane read byte offsets within a panel (fragment m/n adds m*1024)
    const int aro = (wr * 128 + lr) * 64 + ((kq * 16) ^ sx);
    const int bro = (wcn * 64 + lr) * 64 + ((kq * 16) ^ sx);

    f32x4 acc[8][4] = {};

    // prologue: tile 0 panels in FIFO order A-k0, B-k0, A-k1, B-k1
    STAGE_A(0, 0, 0); STAGE_B(0, 0, 0); STAGE_A(0, 1, 0); STAGE_B(0, 1, 0);
    asm volatile("s_waitcnt vmcnt(4)" ::: "memory");   // A-k0,B-k0 complete
    __builtin_amdgcn_s_barrier();

    for (int tt = 0; tt < NT; ++tt) {
        const int cur = tt & 1;
        const int nxt = cur ^ 1;
        const int ko  = (tt + 1) * BK;
        const bool pf = (tt + 1 < NT);
        const char* pA0 = PANEL_A(cur, 0);
        const char* pA1 = PANEL_A(cur, 1);
        const char* pB0 = PANEL_B(cur, 0);
        const char* pB1 = PANEL_B(cur, 1);

        bf16x8 af[4], bf[4];

        // ---- phase 0: quadrant (m0-3, k-half 0); stage A-k0 of tt+1 ----
        #pragma unroll
        for (int m = 0; m < 4; ++m)
            af[m] = *(const bf16x8*)(pA0 + aro + m * 1024);
        #pragma unroll
        for (int n = 0; n < 4; ++n)
            bf[n] = *(const bf16x8*)(pB0 + bro + n * 1024);
        if (pf) STAGE_A(nxt, 0, ko);
        __builtin_amdgcn_s_barrier();
        asm volatile("s_waitcnt lgkmcnt(0)" ::: "memory");
        __builtin_amdgcn_sched_barrier(0);
        __builtin_amdgcn_s_setprio(1);
        #pragma unroll
        for (int m = 0; m < 4; ++m)
            #pragma unroll
            for (int n = 0; n < 4; ++n)
                acc[m][n] = __builtin_amdgcn_mfma_f32_16x16x32_bf16(
                    af[m], bf[n], acc[m][n], 0, 0, 0);
        __builtin_amdgcn_s_setprio(0);
        __builtin_amdgcn_s_barrier();

        // ---- phase 1: quadrant (m4-7, k-half 0); stage B-k0 of tt+1 ----
        #pragma unroll
        for (int m = 0; m < 4; ++m)
            af[m] = *(const bf16x8*)(pA0 + aro + (m + 4) * 1024);
        if (pf) STAGE_B(nxt, 0, ko);
        __builtin_amdgcn_s_barrier();
        asm volatile("s_waitcnt lgkmcnt(0)" ::: "memory");
        __builtin_amdgcn_sched_barrier(0);
        __builtin_amdgcn_s_setprio(1);
        #pragma unroll
        for (int m = 0; m < 4; ++m)
            #pragma unroll
            for (int n = 0; n < 4; ++n)
                acc[m + 4][n] = __builtin_amdgcn_mfma_f32_16x16x32_bf16(
                    af[m], bf[n], acc[m + 4][n], 0, 0, 0);
        __builtin_amdgcn_s_setprio(0);
        if (pf) asm volatile("s_waitcnt vmcnt(4)" ::: "memory"); // tt's k1 panels done
        else    asm volatile("s_waitcnt vmcnt(0)" ::: "memory");
        __builtin_amdgcn_s_barrier();

        // ---- phase 2: quadrant (m0-3, k-half 1); stage A-k1 of tt+1 ----
        #pragma unroll
        for (int m = 0; m < 4; ++m)
            af[m] = *(const bf16x8*)(pA1 + aro + m * 1024);
        #pragma unroll
        for (int n = 0; n < 4; ++n)
            bf[n] = *(const bf16x8*)(pB1 + bro + n * 1024);
        if (pf) STAGE_A(nxt, 1, ko);
        __builtin_amdgcn_s_barrier();
        asm volatile("s_waitcnt lgkmcnt(0)" ::: "memory");
        __builtin_amdgcn_sched_barrier(0);
        __builtin_amdgcn_s_setprio(1);
        #pragma unroll
        for (int m = 0; m < 4; ++m)
            #pragma unroll
            for (int n = 0; n < 4; ++n)
                acc[m][n] = __builtin_amdgcn_mfma_f32_16x16x32_bf16(
                    af[m], bf[n], acc[m][n], 0, 0, 0);
        __builtin_amdgcn_s_setprio(0);
        __builtin_amdgcn_s_barrier();

        // ---- phase 3: quadrant (m4-7, k-half 1); stage B-k1 of tt+1 ----
        #pragma unroll
        for (int m = 0; m < 4; ++m)
            af[m] = *(const bf16x8*)(pA1 + aro + (m + 4) * 1024);
        if (pf) STAGE_B(nxt, 1, ko);
        __builtin_amdgcn_s_barrier();
        asm volatile("s_waitcnt lgkmcnt(0)" ::: "memory");
        __builtin_amdgcn_sched_barrier(0);
        __builtin_amdgcn_s_setprio(1);
        #pragma unroll
        for (int m = 0; m < 4; ++m)
            #pragma unroll
            for (int n = 0; n < 4; ++n)
                acc[m + 4][n] = __builtin_amdgcn_mfma_f32_16x16x32_bf16(
                    af[m], bf[n], acc[m + 4][n], 0, 0, 0);
        __builtin_amdgcn_s_setprio(0);
        if (pf) asm volatile("s_waitcnt vmcnt(4)" ::: "memory"); // tt+1's k0 panels done
        else    asm volatile("s_waitcnt vmcnt(0)" ::: "memory");
        __builtin_amdgcn_s_barrier();
    }

    // ---- epilogue: C/D layout col=lr, row=kq*4+j ----
    #pragma unroll
    for (int n = 0; n < 4; ++n) {
        const int col = bn + wcn * 64 + n * 16 + lr;
        const float bv = bias[col];
        #pragma unroll
        for (int m = 0; m < 8; ++m) {
            const size_t rb = (size_t)(bm + wr * 128 + m * 16 + kq * 4) * OUT_F + col;
            #pragma unroll
            for (int j = 0; j < 4; ++j)
                out[rb + (size_t)j * OUT_F] = acc[m][n][j] + bv;
        }
    }
}

// ---------------------------------------------------------------------------
// Fallback GEMM (round-1 structure, fp32 A reg-staged) for small workspace.
// ---------------------------------------------------------------------------
#define FBM 128
#define FBN 128
#define FBK 32

__global__ __launch_bounds__(256) void gemm_fb_kernel(
    const float* __restrict__ xf,
    const unsigned short* __restrict__ wb,
    const float* __restrict__ bias,
    float* __restrict__ out)
{
    __shared__ unsigned short As[FBM * FBK];
    __shared__ unsigned short Bs[FBN * FBK];

    const int t    = threadIdx.x;
    const int wave = t >> 6;
    const int lane = t & 63;
    const int lr   = lane & 15;
    const int kq   = lane >> 4;
    const int wr   = wave >> 1;
    const int wc   = wave & 1;

    const int bm = blockIdx.x * FBM;
    const int bn = blockIdx.y * FBN;
    const int srow = t >> 2;
    const int scol = (t & 3) * 8;

    f32x4 acc[4][4] = {};

    for (int kt = 0; kt < IN_F; kt += FBK) {
        #pragma unroll
        for (int g = 0; g < 2; ++g) {
            const int row = srow + g * 64;
            const float4* xp = (const float4*)(xf + (size_t)(bm + row) * IN_F + kt + scol);
            const float4 a0 = xp[0], a1 = xp[1];
            const float v[8] = {a0.x, a0.y, a0.z, a0.w, a1.x, a1.y, a1.z, a1.w};
            unsigned int pk[4];
            #pragma unroll
            for (int j = 0; j < 4; ++j)
                pk[j] = (unsigned int)f2bf(v[2*j]) | ((unsigned int)f2bf(v[2*j+1]) << 16);
            *reinterpret_cast<uint4*>(&As[row * FBK + scol]) =
                make_uint4(pk[0], pk[1], pk[2], pk[3]);
        }
        {
            const unsigned short* gb0 = wb + (size_t)(bn + srow) * IN_F + kt + scol;
            const unsigned short* gb1 = gb0 + (size_t)64 * IN_F;
            GLL(gb0, Bs + srow * FBK + scol);
            GLL(gb1, Bs + (64 + srow) * FBK + scol);
        }
        __syncthreads();

        bf16x8 af[4], bfr[4];
        #pragma unroll
        for (int m = 0; m < 4; ++m)
            af[m] = *reinterpret_cast<const bf16x8*>(As + (wr * 64 + m * 16 + lr) * FBK + kq * 8);
        #pragma unroll
        for (int n = 0; n < 4; ++n)
            bfr[n] = *reinterpret_cast<const bf16x8*>(Bs + (wc * 64 + n * 16 + lr) * FBK + kq * 8);

        #pragma unroll
        for (int m = 0; m < 4; ++m)
            #pragma unroll
            for (int n = 0; n < 4; ++n)
                acc[m][n] = __builtin_amdgcn_mfma_f32_16x16x32_bf16(af[m], bfr[n], acc[m][n], 0, 0, 0);

        __syncthreads();
    }

    const int crow0 = kq * 4;
    #pragma unroll
    for (int n = 0; n < 4; ++n) {
        const int col = bn + wc * 64 + n * 16 + lr;
        const float bv = bias[col];
        #pragma unroll
        for (int m = 0; m < 4; ++m) {
            const int rowb = bm + wr * 64 + m * 16 + crow0;
            #pragma unroll
            for (int j = 0; j < 4; ++j)
                out[(size_t)(rowb + j) * OUT_F + col] = acc[m][n][j] + bv;
        }
    }
}

// ---------------------------------------------------------------------------
extern "C" void kernel_launch(void* const* d_in, const int* in_sizes, int n_in,
                              void* d_out, int out_size, void* d_ws, size_t ws_size,
                              hipStream_t stream) {
    const float* x      = (const float*)d_in[0];
    const float* weight = (const float*)d_in[1];
    const float* bias   = (const float*)d_in[2];
    const float* leafs  = (const float*)d_in[3];
    float* out = (float*)d_out;

    unsigned short* wb = (unsigned short*)d_ws;
    unsigned short* xbuf = (unsigned short*)((char*)d_ws +
                           (size_t)OUT_F * IN_F * sizeof(unsigned short));

    const size_t need_full = (size_t)OUT_F * IN_F * 2 + (size_t)M_ROWS * IN_F * 2;
    const bool full = ws_size >= need_full;

    build_w_kernel<<<dim3(2048), dim3(256), 0, stream>>>(weight, leafs, wb);

    if (full) {
        conv_x_kernel<<<dim3(2048), dim3(256), 0, stream>>>(
            x, xbuf, (long long)M_ROWS * IN_F / 8);
        gemm8_kernel<<<dim3((M_ROWS / 256) * (OUT_F / 256)), dim3(512), 0, stream>>>(
            xbuf, wb, bias, out);
    } else {
        gemm_fb_kernel<<<dim3(M_ROWS / FBM, OUT_F / FBN), dim3(256), 0, stream>>>(
            x, wb, bias, out);
    }
}

// Round 3
// 590.154 us; speedup vs baseline: 1.3650x; 1.1028x over previous
//
#include <hip/hip_runtime.h>
#include <hip/hip_bf16.h>
#include <stdint.h>

typedef __attribute__((ext_vector_type(8))) __bf16 bf16x8;
typedef __attribute__((ext_vector_type(4))) float f32x4;

#define IN_F   4096
#define OUT_F  4096
#define M_ROWS 16384   // 8 * 2048

static __device__ __forceinline__ unsigned short f2bf(float f) {
    unsigned int u = __float_as_uint(f);
    u += 0x7FFFu + ((u >> 16) & 1u);   // round-to-nearest-even
    return (unsigned short)(u >> 16);
}

// ---------------------------------------------------------------------------
// Kernel 1: build full weight (OUT_F x IN_F) in bf16.
// ---------------------------------------------------------------------------
__global__ __launch_bounds__(256) void build_w_kernel(
    const float* __restrict__ weight, const float* __restrict__ leafs,
    unsigned short* __restrict__ wb)
{
    __shared__ float s[4][8][8];
    const int t = threadIdx.x;
    {
        const int o = t >> 6, a = (t >> 3) & 7, b = t & 7;
        float acc = 0.f;
        #pragma unroll
        for (int r = 0; r < 8; ++r)
            acc += leafs[o * 512 + r * 64 + a * 8 + b];
        s[o][a][b] = acc;
    }
    __syncthreads();

    const int total = (OUT_F * IN_F) / 8;
    for (int idx = blockIdx.x * 256 + t; idx < total; idx += gridDim.x * 256) {
        const int n  = idx >> 9;
        const int kg = idx & 511;
        const int n0 = n >> 9, n1 = (n >> 6) & 7, n2 = (n >> 3) & 7, n3 = n & 7;
        const int k0 = kg >> 6, k1 = (kg >> 3) & 7, k2 = kg & 7;
        const float p = s[0][k0][n0] * s[1][k1][n1] * s[2][k2][n2];
        const float4* wp = (const float4*)(weight + (size_t)n * IN_F + kg * 8);
        const float4 w0 = wp[0], w1 = wp[1];
        const float wv[8] = {w0.x, w0.y, w0.z, w0.w, w1.x, w1.y, w1.z, w1.w};
        unsigned int pk[4];
        #pragma unroll
        for (int j = 0; j < 4; ++j) {
            unsigned int lo = f2bf(wv[2*j]   + p * s[3][2*j]  [n3]);
            unsigned int hi = f2bf(wv[2*j+1] + p * s[3][2*j+1][n3]);
            pk[j] = lo | (hi << 16);
        }
        *reinterpret_cast<uint4*>(wb + (size_t)n * IN_F + kg * 8) =
            make_uint4(pk[0], pk[1], pk[2], pk[3]);
    }
}

// ---------------------------------------------------------------------------
// Kernel 2: x fp32 -> bf16
// ---------------------------------------------------------------------------
__global__ __launch_bounds__(256) void conv_x_kernel(
    const float* __restrict__ x, unsigned short* __restrict__ xb, long long n8)
{
    for (long long idx = (long long)blockIdx.x * 256 + threadIdx.x; idx < n8;
         idx += (long long)gridDim.x * 256) {
        const float4* xp = (const float4*)(x + idx * 8);
        const float4 a = xp[0], b = xp[1];
        const float v[8] = {a.x, a.y, a.z, a.w, b.x, b.y, b.z, b.w};
        unsigned int pk[4];
        #pragma unroll
        for (int j = 0; j < 4; ++j)
            pk[j] = (unsigned int)f2bf(v[2*j]) | ((unsigned int)f2bf(v[2*j+1]) << 16);
        *reinterpret_cast<uint4*>(xb + idx * 8) = make_uint4(pk[0], pk[1], pk[2], pk[3]);
    }
}

// ---------------------------------------------------------------------------
// Kernel 3: 256x256 8-phase GEMM with cross-phase register prefetch.
// LDS panels: A [2buf][2kk][256][32] at byte 0, B same at 65536 (panel 16KB).
// Element (row,col): byte row*64 + ((col*2) ^ ((row&6)<<3)).
// Schedule per phase: barrier | issue next-subtile ds_reads + 2 GLL |
//   lgkmcnt(4) (waits PREV phase's reads only) | 16 MFMA | [vmcnt] | barrier.
// vmcnt(2) at end of ph0 (drains cur k1 panels) and ph2 (drains nxt k0).
// ---------------------------------------------------------------------------
#define BK 64
#define NT 64

#define PANEL_A(b,kk) (ldsb + ((b)*2+(kk))*16384)
#define PANEL_B(b,kk) (ldsb + 65536 + ((b)*2+(kk))*16384)

#define GLL(src, dst) __builtin_amdgcn_global_load_lds( \
    (const __attribute__((address_space(1))) void*)(src), \
    (__attribute__((address_space(3))) void*)(dst), 16, 0, 0)

#define STAGE_A(b, kk, ko) do { \
    GLL(sA1 + (ko) + (kk)*32,          PANEL_A(b,kk) + d1); \
    GLL(sA1 + 524288 + (ko) + (kk)*32, PANEL_A(b,kk) + d1 + 8192); } while(0)
#define STAGE_B(b, kk, ko) do { \
    GLL(sB1 + (ko) + (kk)*32,          PANEL_B(b,kk) + d1); \
    GLL(sB1 + 524288 + (ko) + (kk)*32, PANEL_B(b,kk) + d1 + 8192); } while(0)

#define SB0  __builtin_amdgcn_sched_barrier(0)
#define BAR  __builtin_amdgcn_s_barrier()
#define PRI1 __builtin_amdgcn_s_setprio(1)
#define PRI0 __builtin_amdgcn_s_setprio(0)
#define WLG4 asm volatile("s_waitcnt lgkmcnt(4)" ::: "memory")
#define WLG0 asm volatile("s_waitcnt lgkmcnt(0)" ::: "memory")
#define WVM2 asm volatile("s_waitcnt vmcnt(2)" ::: "memory")
#define WVM0 asm volatile("s_waitcnt vmcnt(0)" ::: "memory")

#define LDA(dst, BUF, KK, MH) do { _Pragma("unroll") \
    for (int i_ = 0; i_ < 4; ++i_) \
        dst[i_] = *(const bf16x8*)(aB + ((BUF)*32768 + (KK)*16384 + ((MH)*4+i_)*1024)); } while(0)
#define LDB(dst, BUF, KK) do { _Pragma("unroll") \
    for (int i_ = 0; i_ < 4; ++i_) \
        dst[i_] = *(const bf16x8*)(bB + ((BUF)*32768 + (KK)*16384 + i_*1024)); } while(0)
#define MM(AS, MH) do { _Pragma("unroll") \
    for (int m_ = 0; m_ < 4; ++m_) { _Pragma("unroll") \
    for (int n_ = 0; n_ < 4; ++n_) \
        acc[(MH)*4+m_][n_] = __builtin_amdgcn_mfma_f32_16x16x32_bf16( \
            AS[m_], bF[n_], acc[(MH)*4+m_][n_], 0, 0, 0); } } while(0)

#define TILE(BUF, KO, PF) do { \
    /* phase 0: MFMA subtile (m0-3,k0); load bF(k0), aQ(m4-7,k0) */ \
    LDB(bF, BUF, 0); \
    LDA(aQ, BUF, 0, 1); \
    if (PF) STAGE_A((BUF)^1, 0, KO); \
    SB0; WLG4; SB0; \
    PRI1; MM(aP, 0); PRI0; SB0; \
    if (PF) { WVM2; } else { WVM0; } \
    BAR; SB0; \
    /* phase 1: MFMA (m4-7,k0); prefetch aP(m0-3,k1) */ \
    LDA(aP, BUF, 1, 0); \
    if (PF) STAGE_B((BUF)^1, 0, KO); \
    SB0; WLG4; SB0; \
    PRI1; MM(aQ, 1); PRI0; SB0; \
    BAR; SB0; \
    /* phase 2: MFMA (m0-3,k1); load bF(k1), aQ(m4-7,k1) */ \
    LDB(bF, BUF, 1); \
    LDA(aQ, BUF, 1, 1); \
    if (PF) STAGE_A((BUF)^1, 1, KO); \
    SB0; WLG4; SB0; \
    PRI1; MM(aP, 0); PRI0; SB0; \
    if (PF) { WVM2; } else { WVM0; } \
    BAR; SB0; \
    /* phase 3: MFMA (m4-7,k1); prefetch aP(m0-3,k0) of NEXT tile */ \
    if (PF) { LDA(aP, (BUF)^1, 0, 0); STAGE_B((BUF)^1, 1, KO); SB0; WLG4; } \
    else    { SB0; WLG0; } \
    SB0; \
    PRI1; MM(aQ, 1); PRI0; SB0; \
    BAR; SB0; \
} while (0)

__global__ __launch_bounds__(512, 2) void gemm8_kernel(
    const unsigned short* __restrict__ xb,   // bf16 x [M_ROWS][IN_F]
    const unsigned short* __restrict__ wb,   // bf16 W [OUT_F][IN_F]
    const float* __restrict__ bias,
    float* __restrict__ out)
{
    __shared__ unsigned short lds_us[65536];   // 128 KiB
    char* const ldsb = (char*)lds_us;

    const int t    = threadIdx.x;
    const int wave = t >> 6;
    const int lane = t & 63;
    const int lr   = lane & 15;
    const int kq   = lane >> 4;
    const int wr   = wave >> 2;      // 0..1  (M)
    const int wcn  = wave & 3;       // 0..3  (N)
    const int sx   = (lr & 6) << 3;

    // XCD-chunked swizzle; within an XCD chunk: bn-major so A slice stays in
    // that XCD's L2 (2K rows = 4MB) and B streams through L3.
    const int bid  = blockIdx.x;
    const int swzb = (bid & 7) * 128 + (bid >> 3);
    const int bm   = (swzb >> 4) * 256;   // 64 M-tiles
    const int bn   = (swzb & 15) * 256;   // 16 N-tiles

    // staging: thread t covers 16B chunks t and t+512 of each panel (linear)
    const int c1 = t;
    const int r1 = c1 >> 2;                               // panel row (0..127)
    const int q1 = ((c1 & 3) * 16) ^ ((r1 & 6) << 3);     // inv-swizzled src byte
    const unsigned short* sA1 = xb + (size_t)(bm + r1) * IN_F + (q1 >> 1);
    const unsigned short* sB1 = wb + (size_t)(bn + r1) * IN_F + (q1 >> 1);
    const int d1 = c1 * 16;                               // lds dest (linear)
    // chunk 2: row r1+128 -> same swizzle (r&6 unchanged), global +128 rows
    // = +524288 elements; lds dest d1 + 8192.

    // per-lane read bases (swizzled); fragment offsets are immediates
    const char* aB = ldsb + (wr * 128 + lr) * 64 + ((kq * 16) ^ sx);
    const char* bB = ldsb + 65536 + (wcn * 64 + lr) * 64 + ((kq * 16) ^ sx);

    f32x4 acc[8][4] = {};
    bf16x8 aP[4], aQ[4], bF[4];

    // prologue: stage tile 0 (FIFO: A-k0, B-k0, A-k1, B-k1), drain k0, then
    // load subtile 0 regs. Loop invariant entering ph0: vm outstanding = 4
    // (cur tile's k1 panels), lgkm outstanding = 4 (aP reads).
    STAGE_A(0, 0, 0); STAGE_B(0, 0, 0); STAGE_A(0, 1, 0); STAGE_B(0, 1, 0);
    asm volatile("s_waitcnt vmcnt(4)" ::: "memory");
    BAR; SB0;
    LDA(aP, 0, 0, 0);

    #pragma unroll 1
    for (int tt = 0; tt < NT - 2; tt += 2) {
        const int ko0 = (tt + 1) * BK;
        const int ko1 = (tt + 2) * BK;
        TILE(0, ko0, true);
        TILE(1, ko1, true);
    }
    TILE(0, (NT - 1) * BK, true);   // tile 62, stages tile 63
    TILE(1, 0, false);              // tile 63, no staging, conservative waits

    // ---- epilogue: C/D layout col=lr, row=kq*4+j ----
    #pragma unroll
    for (int n = 0; n < 4; ++n) {
        const int col = bn + wcn * 64 + n * 16 + lr;
        const float bv = bias[col];
        #pragma unroll
        for (int m = 0; m < 8; ++m) {
            const size_t rb = (size_t)(bm + wr * 128 + m * 16 + kq * 4) * OUT_F + col;
            #pragma unroll
            for (int j = 0; j < 4; ++j)
                out[rb + (size_t)j * OUT_F] = acc[m][n][j] + bv;
        }
    }
}

// ---------------------------------------------------------------------------
// Fallback GEMM (round-1 structure) for small workspace.
// ---------------------------------------------------------------------------
#define FBM 128
#define FBN 128
#define FBK 32

__global__ __launch_bounds__(256) void gemm_fb_kernel(
    const float* __restrict__ xf,
    const unsigned short* __restrict__ wb,
    const float* __restrict__ bias,
    float* __restrict__ out)
{
    __shared__ unsigned short As[FBM * FBK];
    __shared__ unsigned short Bs[FBN * FBK];

    const int t    = threadIdx.x;
    const int wave = t >> 6;
    const int lane = t & 63;
    const int lr   = lane & 15;
    const int kq   = lane >> 4;
    const int wr   = wave >> 1;
    const int wc   = wave & 1;

    const int bm = blockIdx.x * FBM;
    const int bn = blockIdx.y * FBN;
    const int srow = t >> 2;
    const int scol = (t & 3) * 8;

    f32x4 acc[4][4] = {};

    for (int kt = 0; kt < IN_F; kt += FBK) {
        #pragma unroll
        for (int g = 0; g < 2; ++g) {
            const int row = srow + g * 64;
            const float4* xp = (const float4*)(xf + (size_t)(bm + row) * IN_F + kt + scol);
            const float4 a0 = xp[0], a1 = xp[1];
            const float v[8] = {a0.x, a0.y, a0.z, a0.w, a1.x, a1.y, a1.z, a1.w};
            unsigned int pk[4];
            #pragma unroll
            for (int j = 0; j < 4; ++j)
                pk[j] = (unsigned int)f2bf(v[2*j]) | ((unsigned int)f2bf(v[2*j+1]) << 16);
            *reinterpret_cast<uint4*>(&As[row * FBK + scol]) =
                make_uint4(pk[0], pk[1], pk[2], pk[3]);
        }
        {
            const unsigned short* gb0 = wb + (size_t)(bn + srow) * IN_F + kt + scol;
            const unsigned short* gb1 = gb0 + (size_t)64 * IN_F;
            GLL(gb0, Bs + srow * FBK + scol);
            GLL(gb1, Bs + (64 + srow) * FBK + scol);
        }
        __syncthreads();

        bf16x8 af[4], bfr[4];
        #pragma unroll
        for (int m = 0; m < 4; ++m)
            af[m] = *reinterpret_cast<const bf16x8*>(As + (wr * 64 + m * 16 + lr) * FBK + kq * 8);
        #pragma unroll
        for (int n = 0; n < 4; ++n)
            bfr[n] = *reinterpret_cast<const bf16x8*>(Bs + (wc * 64 + n * 16 + lr) * FBK + kq * 8);

        #pragma unroll
        for (int m = 0; m < 4; ++m)
            #pragma unroll
            for (int n = 0; n < 4; ++n)
                acc[m][n] = __builtin_amdgcn_mfma_f32_16x16x32_bf16(af[m], bfr[n], acc[m][n], 0, 0, 0);

        __syncthreads();
    }

    const int crow0 = kq * 4;
    #pragma unroll
    for (int n = 0; n < 4; ++n) {
        const int col = bn + wc * 64 + n * 16 + lr;
        const float bv = bias[col];
        #pragma unroll
        for (int m = 0; m < 4; ++m) {
            const int rowb = bm + wr * 64 + m * 16 + crow0;
            #pragma unroll
            for (int j = 0; j < 4; ++j)
                out[(size_t)(rowb + j) * OUT_F + col] = acc[m][n][j] + bv;
        }
    }
}

// ---------------------------------------------------------------------------
extern "C" void kernel_launch(void* const* d_in, const int* in_sizes, int n_in,
                              void* d_out, int out_size, void* d_ws, size_t ws_size,
                              hipStream_t stream) {
    const float* x      = (const float*)d_in[0];
    const float* weight = (const float*)d_in[1];
    const float* bias   = (const float*)d_in[2];
    const float* leafs  = (const float*)d_in[3];
    float* out = (float*)d_out;

    unsigned short* wb = (unsigned short*)d_ws;
    unsigned short* xbuf = (unsigned short*)((char*)d_ws +
                           (size_t)OUT_F * IN_F * sizeof(unsigned short));

    const size_t need_full = (size_t)OUT_F * IN_F * 2 + (size_t)M_ROWS * IN_F * 2;
    const bool full = ws_size >= need_full;

    build_w_kernel<<<dim3(2048), dim3(256), 0, stream>>>(weight, leafs, wb);

    if (full) {
        conv_x_kernel<<<dim3(2048), dim3(256), 0, stream>>>(
            x, xbuf, (long long)M_ROWS * IN_F / 8);
        gemm8_kernel<<<dim3((M_ROWS / 256) * (OUT_F / 256)), dim3(512), 0, stream>>>(
            xbuf, wb, bias, out);
    } else {
        gemm_fb_kernel<<<dim3(M_ROWS / FBM, OUT_F / FBN), dim3(256), 0, stream>>>(
            x, wb, bias, out);
    }
}